// Round 12
// baseline (1564.796 us; speedup 1.0000x reference)
//
#include <hip/hip_runtime.h>

#define NPTS 256
#define NBATCH 64
#define BIGF 1e30f
#define KBIG 0x7149F200u   // __float_as_uint(1e30f) & 0xFFFFFF00

__device__ __forceinline__ float rlane(float v, int l) {
    return __uint_as_float((unsigned int)__builtin_amdgcn_readlane((int)__float_as_uint(v), l));
}
__device__ __forceinline__ int rlanei(int v, int l) {
    return __builtin_amdgcn_readlane(v, l);
}
__device__ __forceinline__ float rawsqrt(float x) {
    return __builtin_amdgcn_sqrtf(x);
}
// R24: guaranteed 3-operand fusions (bit-exact by definition of the ops).
// VOP3 forbids literals -> mask passed in a (hoisted) register.
__device__ __forceinline__ unsigned int and_or(unsigned int a, unsigned int m, unsigned int c) {
    unsigned int d;
    asm("v_and_or_b32 %0, %1, %2, %3" : "=v"(d) : "v"(a), "v"(m), "v"(c));
    return d;
}
__device__ __forceinline__ unsigned int min3u(unsigned int a, unsigned int b, unsigned int c) {
    unsigned int d;
    asm("v_min3_u32 %0, %1, %2, %3" : "=v"(d) : "v"(a), "v"(b), "v"(c));
    return d;
}

// Uniform-slot select (slot wave-uniform); cold paths only.
#define SEL4(a, s) ((s) == 0 ? a[0] : (s) == 1 ? a[1] : (s) == 2 ? a[2] : a[3])

#define DPP_UMIN(v, ctrl) \
    (min)((v), (unsigned int)__builtin_amdgcn_update_dpp( \
        (int)(v), (int)(v), (ctrl), 0xf, 0xf, false))

__global__ void zero_out_kernel(float* out, int n) {
    int i = blockIdx.x * blockDim.x + threadIdx.x;
    if (i < n) out[i] = 0.0f;
}

// One expansion step of the delta-accumulated Dijkstra.
// R18: slots 0,1 relax from LDS distance cache (pd01 prefetched last iter);
// slots 2,3 computed FIRST — their math covers the pd01 latency.
// R20: early free-test + single merged fetch/freeze switch.
// R22: prefetch-first arms; usedm -> vv==-BIGF marker.
// R23: 6-DPP reduce (row_shr 1,2,4,8 + row_bcast 15,31) + single readlane(63);
// 4x unrolled loop.
// R24: key-pack via v_and_or_b32 (1 op, was and+or) and pre-reduce via
// v_min3_u32 — inline-asm guaranteed; bit-identical keys.
// REJECTED on analysis: rowdata-in-LDS for the 3 coord readlanes (first
// consumer ~20cy after issue -> ds_read stall would exceed the 6cy saved;
// readlanes have no memory latency). R21 FALSIFIED: post-hoc path
// reconstruction (truncated-key parent match ambiguous -> wrong matching).
// Calibrated model (R17-R23): single wave, in-order, issue-bound; dur moves
// 1:1 with issue+stall cycles per extraction (~150 cy at R23).
#define EXPAND_ONCE                                                              \
    {                                                                            \
        _Pragma("unroll")                                                        \
        for (int c = 2; c < 4; ++c) {                                            \
            float dx = bx - tx[c], dy = by - ty[c], dz = bz - tz[c];             \
            float d = rawsqrt(dx * dx + dy * dy + dz * dz);                      \
            float cand = d + w[c];              /* == d - ukey - vv[c] */        \
            unsigned int kc = and_or(__float_as_uint(cand), kmask, colu[c]);     \
            if (kc < kMv[c]) { kMv[c] = kc; way[c] = j0; }                       \
        }                                                                        \
        {                                                                        \
            float cand0 = pd01.x + w[0];                                         \
            unsigned int kc0 = and_or(__float_as_uint(cand0), kmask, colu[0]);   \
            if (kc0 < kMv[0]) { kMv[0] = kc0; way[0] = j0; }                     \
            float cand1 = pd01.y + w[1];                                         \
            unsigned int kc1 = and_or(__float_as_uint(cand1), kmask, colu[1]);   \
            if (kc1 < kMv[1]) { kMv[1] = kc1; way[1] = j0; }                     \
        }                                                                        \
        unsigned int vr = (min)(min3u(kMv[0], kMv[1], kMv[2]), kMv[3]);          \
        vr = DPP_UMIN(vr, 0x111);   /* row_shr:1 */                              \
        vr = DPP_UMIN(vr, 0x112);   /* row_shr:2 */                              \
        vr = DPP_UMIN(vr, 0x114);   /* row_shr:4 */                              \
        vr = DPP_UMIN(vr, 0x118);   /* row_shr:8 -> lane15/31/47/63 = row min */ \
        vr = DPP_UMIN(vr, 0x142);   /* row_bcast:15 -> lane31,63 pair mins */    \
        vr = DPP_UMIN(vr, 0x143);   /* row_bcast:31 -> lane63 = global min */    \
        const unsigned int kk = (unsigned int)rlanei((int)vr, 63);               \
        const int   j1   = (int)(kk & 0xFFu);                                    \
        const float gmin = __uint_as_float(kk & 0xFFFFFF00u);                    \
        const int osl = j1 >> 6, oln = j1 & 63;                                  \
        const unsigned long long fm = SEL4(freem, osl);                          \
        if ((fm >> oln) & 1ull) { jfin = j1; D = gmin; break; }                  \
        float uj, nbx, nby, nbz; int prow;                                       \
        switch (osl) {                                                           \
            case 0:                                                              \
                prow = rlanei(pc[0], oln);                                       \
                pd01 = dcache[prow * 64 + lane];                                 \
                uj = rlane(upc[0], oln); nbx = rlane(rxc[0], oln);               \
                nby = rlane(ryc[0], oln); nbz = rlane(rzc[0], oln);              \
                if (lane == oln) {                                               \
                    Tv[0] = gmin; vsave[0] = vv[0];                              \
                    vv[0] = -BIGF; kMv[0] = KBIG | colu[0];                      \
                }                                                                \
                break;                                                           \
            case 1:                                                              \
                prow = rlanei(pc[1], oln);                                       \
                pd01 = dcache[prow * 64 + lane];                                 \
                uj = rlane(upc[1], oln); nbx = rlane(rxc[1], oln);               \
                nby = rlane(ryc[1], oln); nbz = rlane(rzc[1], oln);              \
                if (lane == oln) {                                               \
                    Tv[1] = gmin; vsave[1] = vv[1];                              \
                    vv[1] = -BIGF; kMv[1] = KBIG | colu[1];                      \
                }                                                                \
                break;                                                           \
            case 2:                                                              \
                prow = rlanei(pc[2], oln);                                       \
                pd01 = dcache[prow * 64 + lane];                                 \
                uj = rlane(upc[2], oln); nbx = rlane(rxc[2], oln);               \
                nby = rlane(ryc[2], oln); nbz = rlane(rzc[2], oln);              \
                if (lane == oln) {                                               \
                    Tv[2] = gmin; vsave[2] = vv[2];                              \
                    vv[2] = -BIGF; kMv[2] = KBIG | colu[2];                      \
                }                                                                \
                break;                                                           \
            default:                                                             \
                prow = rlanei(pc[3], oln);                                       \
                pd01 = dcache[prow * 64 + lane];                                 \
                uj = rlane(upc[3], oln); nbx = rlane(rxc[3], oln);               \
                nby = rlane(ryc[3], oln); nbz = rlane(rzc[3], oln);              \
                if (lane == oln) {                                               \
                    Tv[3] = gmin; vsave[3] = vv[3];                              \
                    vv[3] = -BIGF; kMv[3] = KBIG | colu[3];                      \
                }                                                                \
                break;                                                           \
        }                                                                        \
        const float gu = gmin - uj;                                              \
        _Pragma("unroll")                                                        \
        for (int c = 0; c < 4; ++c) w[c] = gu - vv[c];                           \
        bx = nbx; by = nby; bz = nbz;                                            \
        j0 = j1;                                                                 \
    }

// One wave per batch; lane owns columns/rows {lane, 64+lane, 128+lane, 192+lane}.
// JV: column reduction -> greedy claim -> delta-accumulated Dijkstra searches.
// R24 = R23 + v_and_or_b32 / v_min3_u32 fusions in the hot loop.
__launch_bounds__(64, 1)
__global__ void hungarian_wave(const float* __restrict__ pred,
                               const float* __restrict__ target,
                               float* __restrict__ out) {
    const int b    = blockIdx.x;
    const int lane = threadIdx.x;

    __shared__ float2 dcache[NPTS * 64];   // [row][lane] -> d(row, lane), d(row, 64+lane); 128KB

    const float* pb = pred   + (size_t)b * NPTS * 3;
    const float* tb = target + (size_t)b * NPTS * 3;

    float prx[4], pry[4], prz[4];      // pred (row) points, row = c*64+lane
    float tx[4], ty[4], tz[4];         // target (col) points, col = c*64+lane
    float vv[4], upc[4], Tv[4], w[4], vsave[4];
    float rxc[4], ryc[4], rzc[4];      // matched-row coords, column-attached
    unsigned int kMv[4];               // packed slack keys: (bits(M)&~0xFF)|col
    int   pc[4]  = {-1, -1, -1, -1};   // matched row per column (-1 = free)
    int   way[4];
    unsigned int colu[4];              // this lane's column ids
    unsigned long long freem[4];       // free-COLUMN masks (wave-uniform)
    const unsigned int kmask = 0xFFFFFF00u;   // hoisted for v_and_or_b32 (VOP3: no literal)

#pragma unroll
    for (int c = 0; c < 4; ++c) {
        int idx = c * 64 + lane;
        prx[c] = pb[idx * 3 + 0]; pry[c] = pb[idx * 3 + 1]; prz[c] = pb[idx * 3 + 2];
        tx[c]  = tb[idx * 3 + 0]; ty[c]  = tb[idx * 3 + 1]; tz[c]  = tb[idx * 3 + 2];
        upc[c] = 0.f; Tv[c] = 0.f; vsave[c] = 0.f;
        rxc[c] = 0.f; ryc[c] = 0.f; rzc[c] = 0.f;
        colu[c] = (unsigned int)idx;
        freem[c] = ~0ull;
    }

    // ---- Phase 1a: column reduction + distance-cache fill for slots 0,1 ----
    float colmin[4] = {BIGF, BIGF, BIGF, BIGF};
    int   colrow[4] = {0, 0, 0, 0};
#pragma unroll
    for (int rs = 0; rs < 4; ++rs) {
        for (int rl = 0; rl < 64; ++rl) {
            float bx = rlane(prx[rs], rl), by = rlane(pry[rs], rl), bz = rlane(prz[rs], rl);
            int r = rs * 64 + rl;
            float dd[4];
#pragma unroll
            for (int c = 0; c < 4; ++c) {
                float dx = bx - tx[c], dy = by - ty[c], dz = bz - tz[c];
                dd[c] = rawsqrt(dx * dx + dy * dy + dz * dz);
                if (dd[c] < colmin[c]) { colmin[c] = dd[c]; colrow[c] = r; }
            }
            dcache[r * 64 + lane] = make_float2(dd[0], dd[1]);
        }
    }
#pragma unroll
    for (int c = 0; c < 4; ++c) vv[c] = colmin[c];
    __syncthreads();   // single wave: near-free; orders dcache writes vs reads

    // ---- Phase 1b: greedy claim — column (ascending) claims its argmin row if free ----
    unsigned long long frm[4];         // free-row masks (wave-uniform values)
    frm[0] = frm[1] = frm[2] = frm[3] = ~0ull;
#pragma unroll
    for (int cs = 0; cs < 4; ++cs) {
        for (int l = 0; l < 64; ++l) {
            int r = rlanei(colrow[cs], l);
            int rs = r >> 6, rl2 = r & 63;
            unsigned long long bit = 1ull << rl2;
            bool free_row = (SEL4(frm, rs) & bit) != 0ull;
            if (free_row) {
#pragma unroll
                for (int s = 0; s < 4; ++s)
                    if (s == rs) frm[s] &= ~bit;
                float bx, by, bz;
                switch (rs) {
                    case 0:  bx = rlane(prx[0], rl2); by = rlane(pry[0], rl2); bz = rlane(prz[0], rl2); break;
                    case 1:  bx = rlane(prx[1], rl2); by = rlane(pry[1], rl2); bz = rlane(prz[1], rl2); break;
                    case 2:  bx = rlane(prx[2], rl2); by = rlane(pry[2], rl2); bz = rlane(prz[2], rl2); break;
                    default: bx = rlane(prx[3], rl2); by = rlane(pry[3], rl2); bz = rlane(prz[3], rl2); break;
                }
                if (lane == l) {
                    pc[cs] = r; upc[cs] = 0.f;
                    rxc[cs] = bx; ryc[cs] = by; rzc[cs] = bz;
                }
#pragma unroll
                for (int s = 0; s < 4; ++s)
                    if (s == cs) freem[s] &= ~(1ull << l);   // column cs*64+l matched
            }
        }
    }

    // ---- Phase 2: Dijkstra shortest-path for remaining free rows ----
#pragma unroll
    for (int is = 0; is < 4; ++is) {
        unsigned long long m = frm[is];
        while (m) {
            const int il = (int)__builtin_ctzll(m);
            m &= (m - 1);
            const int i = is * 64 + il;

            float rootx, rooty, rootz;
            switch (is) {
                case 0:  rootx = rlane(prx[0], il); rooty = rlane(pry[0], il); rootz = rlane(prz[0], il); break;
                case 1:  rootx = rlane(prx[1], il); rooty = rlane(pry[1], il); rootz = rlane(prz[1], il); break;
                case 2:  rootx = rlane(prx[2], il); rooty = rlane(pry[2], il); rootz = rlane(prz[2], il); break;
                default: rootx = rlane(prx[3], il); rooty = rlane(pry[3], il); rootz = rlane(prz[3], il); break;
            }

#pragma unroll
            for (int c = 0; c < 4; ++c) {
                kMv[c] = KBIG | colu[c];
                w[c]   = -vv[c];
            }

            float bx = rootx, by = rooty, bz = rootz;
            float2 pd01 = dcache[i * 64 + lane];   // root row's cached d0,d1
            int j0 = -1;
            int jfin = 0;
            float D = 0.f;

            while (true) {
                EXPAND_ONCE
                EXPAND_ONCE
                EXPAND_ONCE
                EXPAND_ONCE
            }

            // Commit duals for tree columns (marker: vv[c] == -BIGF, set only
            // at freeze; legit duals are finite small): net = D_final - D_at_use
#pragma unroll
            for (int c = 0; c < 4; ++c)
                if (vv[c] == -BIGF) {
                    vv[c] = vsave[c] + Tv[c] - D;
                    upc[c] += D - Tv[c];
                }

            // Newly matched column leaves the free set
            {
                const int wsl = jfin >> 6;
                const unsigned long long bit = 1ull << (jfin & 63);
#pragma unroll
                for (int s = 0; s < 4; ++s)
                    if (s == wsl) freem[s] &= ~bit;
            }

            // Augment along alternating path (cold)
            int jc = jfin;
            while (true) {
                const int osl = jc >> 6, oln = jc & 63;
                int jw;
                switch (osl) {
                    case 0:  jw = rlanei(way[0], oln); break;
                    case 1:  jw = rlanei(way[1], oln); break;
                    case 2:  jw = rlanei(way[2], oln); break;
                    default: jw = rlanei(way[3], oln); break;
                }
                int np_; float nup, nrx, nry, nrz;
                if (jw < 0) {
                    np_ = i; nup = D; nrx = rootx; nry = rooty; nrz = rootz;
                } else {
                    const int wsl = jw >> 6, wln = jw & 63;
                    switch (wsl) {
                        case 0:  np_ = rlanei(pc[0], wln); nup = rlane(upc[0], wln); nrx = rlane(rxc[0], wln); nry = rlane(ryc[0], wln); nrz = rlane(rzc[0], wln); break;
                        case 1:  np_ = rlanei(pc[1], wln); nup = rlane(upc[1], wln); nrx = rlane(rxc[1], wln); nry = rlane(ryc[1], wln); nrz = rlane(rzc[1], wln); break;
                        case 2:  np_ = rlanei(pc[2], wln); nup = rlane(upc[2], wln); nrx = rlane(rxc[2], wln); nry = rlane(ryc[2], wln); nrz = rlane(rzc[2], wln); break;
                        default: np_ = rlanei(pc[3], wln); nup = rlane(upc[3], wln); nrx = rlane(rxc[3], wln); nry = rlane(ryc[3], wln); nrz = rlane(rzc[3], wln); break;
                    }
                }
#pragma unroll
                for (int c = 0; c < 4; ++c)
                    if (c == osl && lane == oln) {
                        pc[c] = np_; upc[c] = nup;
                        rxc[c] = nrx; ryc[c] = nry; rzc[c] = nrz;
                    }
                if (jw < 0) break;
                jc = jw;
            }
        }
    }

    // ---- Matched cost (coords column-attached; IEEE sqrt for final accuracy) ----
    float s = 0.f;
#pragma unroll
    for (int c = 0; c < 4; ++c) {
        float dx = rxc[c] - tx[c], dy = ryc[c] - ty[c], dz = rzc[c] - tz[c];
        s += sqrtf(dx * dx + dy * dy + dz * dz);
    }
#pragma unroll
    for (int off = 1; off < 64; off <<= 1) s += __shfl_xor(s, off, 64);
    if (lane == 0) atomicAdd(out, s / (float)NBATCH);
}

extern "C" void kernel_launch(void* const* d_in, const int* in_sizes, int n_in,
                              void* d_out, int out_size, void* d_ws, size_t ws_size,
                              hipStream_t stream) {
    const float* pred   = (const float*)d_in[0];
    const float* target = (const float*)d_in[1];
    float* out = (float*)d_out;

    zero_out_kernel<<<1, 64, 0, stream>>>(out, out_size);
    hungarian_wave<<<NBATCH, 64, 0, stream>>>(pred, target, out);
}

// Round 13
// 1538.349 us; speedup vs baseline: 1.0172x; 1.0172x over previous
//
#include <hip/hip_runtime.h>

#define NPTS 256
#define NBATCH 64
#define BIGF 1e30f
#define KBIG 0x7149F200u   // __float_as_uint(1e30f) & 0xFFFFFF00

__device__ __forceinline__ float rlane(float v, int l) {
    return __uint_as_float((unsigned int)__builtin_amdgcn_readlane((int)__float_as_uint(v), l));
}
__device__ __forceinline__ int rlanei(int v, int l) {
    return __builtin_amdgcn_readlane(v, l);
}
__device__ __forceinline__ float rawsqrt(float x) {
    return __builtin_amdgcn_sqrtf(x);
}

// Uniform-slot select (slot wave-uniform); cold paths only.
#define SEL4(a, s) ((s) == 0 ? a[0] : (s) == 1 ? a[1] : (s) == 2 ? a[2] : a[3])

#define DPP_UMIN(v, ctrl) \
    (min)((v), (unsigned int)__builtin_amdgcn_update_dpp( \
        (int)(v), (int)(v), (ctrl), 0xf, 0xf, false))

__global__ void zero_out_kernel(float* out, int n) {
    int i = blockIdx.x * blockDim.x + threadIdx.x;
    if (i < n) out[i] = 0.0f;
}

// One expansion step of the delta-accumulated Dijkstra.
// R18: slots 0,1 relax from LDS distance cache (pd01 prefetched last iter);
// slots 2,3 computed — filler for the prefetch latency.
// R20: early free-test + single merged fetch/freeze switch.
// R22: prefetch-first arms; usedm -> vv==-BIGF marker.
// R23: reduce = 6 DPP stages (row_shr 1,2,4,8 + row_bcast 15,31) + single
// readlane(63); 4x unrolled loop. BEST VERIFIED: 1540.8us total / 1505.7 hot.
// R24 FALSIFIED (reverted): inline-asm v_and_or_b32/v_min3_u32 — compiler
// already fuses; asm constraints cost +0.6%. R21 FALSIFIED: post-hoc path
// reconstruction (truncated-key parent match ambiguous -> wrong matching);
// way maintenance is the price of exactness.
// FINAL calibrated model (R17-R24): single wave per batch, in-order,
// issue-bound (~150 cy/extraction, ~26k extractions on the critical batch).
// Falsified macro levers: R14 dual strengthening, R15 multi-source SSP,
// R16 free-argmin claims, R17 cross-problem ILP. This is the dependent-chain
// floor of an exact serial algorithm — latency-bound, not a HW roofline
// (VALUBusy 2.2%, HBM 0.004%).
#define EXPAND_ONCE                                                              \
    {                                                                            \
        _Pragma("unroll")                                                        \
        for (int c = 2; c < 4; ++c) {                                            \
            float dx = bx - tx[c], dy = by - ty[c], dz = bz - tz[c];             \
            float d = rawsqrt(dx * dx + dy * dy + dz * dz);                      \
            float cand = d + w[c];              /* == d - ukey - vv[c] */        \
            unsigned int kc = (__float_as_uint(cand) & 0xFFFFFF00u) | colu[c];   \
            if (kc < kMv[c]) { kMv[c] = kc; way[c] = j0; }                       \
        }                                                                        \
        {                                                                        \
            float cand0 = pd01.x + w[0];                                         \
            unsigned int kc0 = (__float_as_uint(cand0) & 0xFFFFFF00u) | colu[0]; \
            if (kc0 < kMv[0]) { kMv[0] = kc0; way[0] = j0; }                     \
            float cand1 = pd01.y + w[1];                                         \
            unsigned int kc1 = (__float_as_uint(cand1) & 0xFFFFFF00u) | colu[1]; \
            if (kc1 < kMv[1]) { kMv[1] = kc1; way[1] = j0; }                     \
        }                                                                        \
        unsigned int vr = (min)((min)(kMv[0], kMv[1]), (min)(kMv[2], kMv[3]));   \
        vr = DPP_UMIN(vr, 0x111);   /* row_shr:1 */                              \
        vr = DPP_UMIN(vr, 0x112);   /* row_shr:2 */                              \
        vr = DPP_UMIN(vr, 0x114);   /* row_shr:4 */                              \
        vr = DPP_UMIN(vr, 0x118);   /* row_shr:8 -> lane15/31/47/63 = row min */ \
        vr = DPP_UMIN(vr, 0x142);   /* row_bcast:15 -> lane31,63 pair mins */    \
        vr = DPP_UMIN(vr, 0x143);   /* row_bcast:31 -> lane63 = global min */    \
        const unsigned int kk = (unsigned int)rlanei((int)vr, 63);               \
        const int   j1   = (int)(kk & 0xFFu);                                    \
        const float gmin = __uint_as_float(kk & 0xFFFFFF00u);                    \
        const int osl = j1 >> 6, oln = j1 & 63;                                  \
        const unsigned long long fm = SEL4(freem, osl);                          \
        if ((fm >> oln) & 1ull) { jfin = j1; D = gmin; break; }                  \
        float uj, nbx, nby, nbz; int prow;                                       \
        switch (osl) {                                                           \
            case 0:                                                              \
                prow = rlanei(pc[0], oln);                                       \
                pd01 = dcache[prow * 64 + lane];                                 \
                uj = rlane(upc[0], oln); nbx = rlane(rxc[0], oln);               \
                nby = rlane(ryc[0], oln); nbz = rlane(rzc[0], oln);              \
                if (lane == oln) {                                               \
                    Tv[0] = gmin; vsave[0] = vv[0];                              \
                    vv[0] = -BIGF; kMv[0] = KBIG | colu[0];                      \
                }                                                                \
                break;                                                           \
            case 1:                                                              \
                prow = rlanei(pc[1], oln);                                       \
                pd01 = dcache[prow * 64 + lane];                                 \
                uj = rlane(upc[1], oln); nbx = rlane(rxc[1], oln);               \
                nby = rlane(ryc[1], oln); nbz = rlane(rzc[1], oln);              \
                if (lane == oln) {                                               \
                    Tv[1] = gmin; vsave[1] = vv[1];                              \
                    vv[1] = -BIGF; kMv[1] = KBIG | colu[1];                      \
                }                                                                \
                break;                                                           \
            case 2:                                                              \
                prow = rlanei(pc[2], oln);                                       \
                pd01 = dcache[prow * 64 + lane];                                 \
                uj = rlane(upc[2], oln); nbx = rlane(rxc[2], oln);               \
                nby = rlane(ryc[2], oln); nbz = rlane(rzc[2], oln);              \
                if (lane == oln) {                                               \
                    Tv[2] = gmin; vsave[2] = vv[2];                              \
                    vv[2] = -BIGF; kMv[2] = KBIG | colu[2];                      \
                }                                                                \
                break;                                                           \
            default:                                                             \
                prow = rlanei(pc[3], oln);                                       \
                pd01 = dcache[prow * 64 + lane];                                 \
                uj = rlane(upc[3], oln); nbx = rlane(rxc[3], oln);               \
                nby = rlane(ryc[3], oln); nbz = rlane(rzc[3], oln);              \
                if (lane == oln) {                                               \
                    Tv[3] = gmin; vsave[3] = vv[3];                              \
                    vv[3] = -BIGF; kMv[3] = KBIG | colu[3];                      \
                }                                                                \
                break;                                                           \
        }                                                                        \
        const float gu = gmin - uj;                                              \
        _Pragma("unroll")                                                        \
        for (int c = 0; c < 4; ++c) w[c] = gu - vv[c];                           \
        bx = nbx; by = nby; bz = nbz;                                            \
        j0 = j1;                                                                 \
    }

// One wave per batch; lane owns columns/rows {lane, 64+lane, 128+lane, 192+lane}.
// JV: column reduction -> greedy claim -> delta-accumulated Dijkstra searches.
// R25 = R23 (revert of R24's inline-asm fusions). Final kernel.
__launch_bounds__(64, 1)
__global__ void hungarian_wave(const float* __restrict__ pred,
                               const float* __restrict__ target,
                               float* __restrict__ out) {
    const int b    = blockIdx.x;
    const int lane = threadIdx.x;

    __shared__ float2 dcache[NPTS * 64];   // [row][lane] -> d(row, lane), d(row, 64+lane); 128KB

    const float* pb = pred   + (size_t)b * NPTS * 3;
    const float* tb = target + (size_t)b * NPTS * 3;

    float prx[4], pry[4], prz[4];      // pred (row) points, row = c*64+lane
    float tx[4], ty[4], tz[4];         // target (col) points, col = c*64+lane
    float vv[4], upc[4], Tv[4], w[4], vsave[4];
    float rxc[4], ryc[4], rzc[4];      // matched-row coords, column-attached
    unsigned int kMv[4];               // packed slack keys: (bits(M)&~0xFF)|col
    int   pc[4]  = {-1, -1, -1, -1};   // matched row per column (-1 = free)
    int   way[4];
    unsigned int colu[4];              // this lane's column ids
    unsigned long long freem[4];       // free-COLUMN masks (wave-uniform)

#pragma unroll
    for (int c = 0; c < 4; ++c) {
        int idx = c * 64 + lane;
        prx[c] = pb[idx * 3 + 0]; pry[c] = pb[idx * 3 + 1]; prz[c] = pb[idx * 3 + 2];
        tx[c]  = tb[idx * 3 + 0]; ty[c]  = tb[idx * 3 + 1]; tz[c]  = tb[idx * 3 + 2];
        upc[c] = 0.f; Tv[c] = 0.f; vsave[c] = 0.f;
        rxc[c] = 0.f; ryc[c] = 0.f; rzc[c] = 0.f;
        colu[c] = (unsigned int)idx;
        freem[c] = ~0ull;
    }

    // ---- Phase 1a: column reduction + distance-cache fill for slots 0,1 ----
    float colmin[4] = {BIGF, BIGF, BIGF, BIGF};
    int   colrow[4] = {0, 0, 0, 0};
#pragma unroll
    for (int rs = 0; rs < 4; ++rs) {
        for (int rl = 0; rl < 64; ++rl) {
            float bx = rlane(prx[rs], rl), by = rlane(pry[rs], rl), bz = rlane(prz[rs], rl);
            int r = rs * 64 + rl;
            float dd[4];
#pragma unroll
            for (int c = 0; c < 4; ++c) {
                float dx = bx - tx[c], dy = by - ty[c], dz = bz - tz[c];
                dd[c] = rawsqrt(dx * dx + dy * dy + dz * dz);
                if (dd[c] < colmin[c]) { colmin[c] = dd[c]; colrow[c] = r; }
            }
            dcache[r * 64 + lane] = make_float2(dd[0], dd[1]);
        }
    }
#pragma unroll
    for (int c = 0; c < 4; ++c) vv[c] = colmin[c];
    __syncthreads();   // single wave: near-free; orders dcache writes vs reads

    // ---- Phase 1b: greedy claim — column (ascending) claims its argmin row if free ----
    unsigned long long frm[4];         // free-row masks (wave-uniform values)
    frm[0] = frm[1] = frm[2] = frm[3] = ~0ull;
#pragma unroll
    for (int cs = 0; cs < 4; ++cs) {
        for (int l = 0; l < 64; ++l) {
            int r = rlanei(colrow[cs], l);
            int rs = r >> 6, rl2 = r & 63;
            unsigned long long bit = 1ull << rl2;
            bool free_row = (SEL4(frm, rs) & bit) != 0ull;
            if (free_row) {
#pragma unroll
                for (int s = 0; s < 4; ++s)
                    if (s == rs) frm[s] &= ~bit;
                float bx, by, bz;
                switch (rs) {
                    case 0:  bx = rlane(prx[0], rl2); by = rlane(pry[0], rl2); bz = rlane(prz[0], rl2); break;
                    case 1:  bx = rlane(prx[1], rl2); by = rlane(pry[1], rl2); bz = rlane(prz[1], rl2); break;
                    case 2:  bx = rlane(prx[2], rl2); by = rlane(pry[2], rl2); bz = rlane(prz[2], rl2); break;
                    default: bx = rlane(prx[3], rl2); by = rlane(pry[3], rl2); bz = rlane(prz[3], rl2); break;
                }
                if (lane == l) {
                    pc[cs] = r; upc[cs] = 0.f;
                    rxc[cs] = bx; ryc[cs] = by; rzc[cs] = bz;
                }
#pragma unroll
                for (int s = 0; s < 4; ++s)
                    if (s == cs) freem[s] &= ~(1ull << l);   // column cs*64+l matched
            }
        }
    }

    // ---- Phase 2: Dijkstra shortest-path for remaining free rows ----
#pragma unroll
    for (int is = 0; is < 4; ++is) {
        unsigned long long m = frm[is];
        while (m) {
            const int il = (int)__builtin_ctzll(m);
            m &= (m - 1);
            const int i = is * 64 + il;

            float rootx, rooty, rootz;
            switch (is) {
                case 0:  rootx = rlane(prx[0], il); rooty = rlane(pry[0], il); rootz = rlane(prz[0], il); break;
                case 1:  rootx = rlane(prx[1], il); rooty = rlane(pry[1], il); rootz = rlane(prz[1], il); break;
                case 2:  rootx = rlane(prx[2], il); rooty = rlane(pry[2], il); rootz = rlane(prz[2], il); break;
                default: rootx = rlane(prx[3], il); rooty = rlane(pry[3], il); rootz = rlane(prz[3], il); break;
            }

#pragma unroll
            for (int c = 0; c < 4; ++c) {
                kMv[c] = KBIG | colu[c];
                w[c]   = -vv[c];
            }

            float bx = rootx, by = rooty, bz = rootz;
            float2 pd01 = dcache[i * 64 + lane];   // root row's cached d0,d1
            int j0 = -1;
            int jfin = 0;
            float D = 0.f;

            while (true) {
                EXPAND_ONCE
                EXPAND_ONCE
                EXPAND_ONCE
                EXPAND_ONCE
            }

            // Commit duals for tree columns (marker: vv[c] == -BIGF, set only
            // at freeze; legit duals are finite small): net = D_final - D_at_use
#pragma unroll
            for (int c = 0; c < 4; ++c)
                if (vv[c] == -BIGF) {
                    vv[c] = vsave[c] + Tv[c] - D;
                    upc[c] += D - Tv[c];
                }

            // Newly matched column leaves the free set
            {
                const int wsl = jfin >> 6;
                const unsigned long long bit = 1ull << (jfin & 63);
#pragma unroll
                for (int s = 0; s < 4; ++s)
                    if (s == wsl) freem[s] &= ~bit;
            }

            // Augment along alternating path (cold)
            int jc = jfin;
            while (true) {
                const int osl = jc >> 6, oln = jc & 63;
                int jw;
                switch (osl) {
                    case 0:  jw = rlanei(way[0], oln); break;
                    case 1:  jw = rlanei(way[1], oln); break;
                    case 2:  jw = rlanei(way[2], oln); break;
                    default: jw = rlanei(way[3], oln); break;
                }
                int np_; float nup, nrx, nry, nrz;
                if (jw < 0) {
                    np_ = i; nup = D; nrx = rootx; nry = rooty; nrz = rootz;
                } else {
                    const int wsl = jw >> 6, wln = jw & 63;
                    switch (wsl) {
                        case 0:  np_ = rlanei(pc[0], wln); nup = rlane(upc[0], wln); nrx = rlane(rxc[0], wln); nry = rlane(ryc[0], wln); nrz = rlane(rzc[0], wln); break;
                        case 1:  np_ = rlanei(pc[1], wln); nup = rlane(upc[1], wln); nrx = rlane(rxc[1], wln); nry = rlane(ryc[1], wln); nrz = rlane(rzc[1], wln); break;
                        case 2:  np_ = rlanei(pc[2], wln); nup = rlane(upc[2], wln); nrx = rlane(rxc[2], wln); nry = rlane(ryc[2], wln); nrz = rlane(rzc[2], wln); break;
                        default: np_ = rlanei(pc[3], wln); nup = rlane(upc[3], wln); nrx = rlane(rxc[3], wln); nry = rlane(ryc[3], wln); nrz = rlane(rzc[3], wln); break;
                    }
                }
#pragma unroll
                for (int c = 0; c < 4; ++c)
                    if (c == osl && lane == oln) {
                        pc[c] = np_; upc[c] = nup;
                        rxc[c] = nrx; ryc[c] = nry; rzc[c] = nrz;
                    }
                if (jw < 0) break;
                jc = jw;
            }
        }
    }

    // ---- Matched cost (coords column-attached; IEEE sqrt for final accuracy) ----
    float s = 0.f;
#pragma unroll
    for (int c = 0; c < 4; ++c) {
        float dx = rxc[c] - tx[c], dy = ryc[c] - ty[c], dz = rzc[c] - tz[c];
        s += sqrtf(dx * dx + dy * dy + dz * dz);
    }
#pragma unroll
    for (int off = 1; off < 64; off <<= 1) s += __shfl_xor(s, off, 64);
    if (lane == 0) atomicAdd(out, s / (float)NBATCH);
}

extern "C" void kernel_launch(void* const* d_in, const int* in_sizes, int n_in,
                              void* d_out, int out_size, void* d_ws, size_t ws_size,
                              hipStream_t stream) {
    const float* pred   = (const float*)d_in[0];
    const float* target = (const float*)d_in[1];
    float* out = (float*)d_out;

    zero_out_kernel<<<1, 64, 0, stream>>>(out, out_size);
    hungarian_wave<<<NBATCH, 64, 0, stream>>>(pred, target, out);
}